// Round 11
// baseline (287.065 us; speedup 1.0000x reference)
//
#include <hip/hip_runtime.h>
#include <hip/hip_bf16.h>
#include <math.h>

#define B_  32
#define N_  512
#define C_  384
#define H_  6
#define HD_ 64
#define M_  (B_*N_)   // 16384 rows

typedef __attribute__((ext_vector_type(8))) short bfrag;   // 8 bf16 (4 VGPRs)
typedef __attribute__((ext_vector_type(4))) float f32x4;   // mfma C/D
typedef unsigned short bfraw;

__device__ __forceinline__ float bfu2f(unsigned short u){
  return __uint_as_float(((unsigned int)u) << 16);
}
__device__ __forceinline__ unsigned short f2bfu(float f){
  unsigned int u = __float_as_uint(f);
  u += 0x7fffu + ((u >> 16) & 1u);   // round-to-nearest-even
  return (unsigned short)(u >> 16);
}
__device__ __forceinline__ bfrag cvt8(float4 a, float4 b){
  bfrag r;
  r[0]=(short)f2bfu(a.x); r[1]=(short)f2bfu(a.y); r[2]=(short)f2bfu(a.z); r[3]=(short)f2bfu(a.w);
  r[4]=(short)f2bfu(b.x); r[5]=(short)f2bfu(b.y); r[6]=(short)f2bfu(b.z); r[7]=(short)f2bfu(b.w);
  return r;
}

// ---------------- params ----------------
__global__ void param_kernel(const float* __restrict__ scale_p,
                             const float* __restrict__ power_p,
                             float* __restrict__ scale_inv,
                             float* __restrict__ power){
  int t = threadIdx.x;
  if (t < C_){
    float s  = scale_p[t];
    scale_inv[t] = 1.0f / log1pf(expf(s));   // 1/softplus
  }
  if (t < H_*HD_){
    float p = power_p[t];
    power[t] = 1.0f + 4.0f / (1.0f + expf(-p));
  }
}

__global__ void sentinel_kernel(float* __restrict__ out, int n){
  int i = blockIdx.x*256 + threadIdx.x;
  if (i < n) out[i] = 1.0e9f;
}

// ---------------- qkvg GEMM, MFMA bf16: 128x384 tile (full N), 8 waves (2x4), bf16 out ----
// mode 0: q = (y @ W0^T + b0) * scale_inv
// mode 1: k = ((x @ W1^T + b1) + pe) * scale_inv
// mode 2: v =  x @ W2^T + b2
// mode 3: g =  x @ W3^T + b3
__global__ __launch_bounds__(512) void gemm_qkvg(
    const float* __restrict__ x, const float* __restrict__ y,
    const float* __restrict__ W, const float* __restrict__ bias,
    const float* __restrict__ pe, const float* __restrict__ scale_inv,
    bfraw* __restrict__ q, bfraw* __restrict__ k, bfraw* __restrict__ v,
    bfraw* __restrict__ g)
{
  const int mode = blockIdx.y;
  const float* A = (mode == 0) ? y : x;
  const int wofs = mode * C_;
  bfraw* out = (mode==0)?q:((mode==1)?k:((mode==2)?v:g));

  __shared__ short As[128][40];   // 10.2 KB
  __shared__ short Bs[384][40];   // 30.7 KB

  const int tid  = threadIdx.x;
  const int row0 = blockIdx.x * 128;
  const int wave = tid >> 6, lane = tid & 63;
  const int wm = (wave >> 2) * 64;       // 0 or 64
  const int wn = (wave & 3) * 96;        // 0,96,192,288
  const int fr = lane & 15, quad = lane >> 4;
  const int sr = tid >> 2;               // 0..127
  const int sk = (tid & 3) * 8;          // 0,8,16,24

  f32x4 acc[4][6] = {};

  for (int k0 = 0; k0 < C_; k0 += 32){
    {
      const float* ap = &A[(size_t)(row0 + sr)*C_ + k0 + sk];
      float4 a0 = *reinterpret_cast<const float4*>(ap);
      float4 a1 = *reinterpret_cast<const float4*>(ap + 4);
      *reinterpret_cast<bfrag*>(&As[sr][sk]) = cvt8(a0, a1);
    }
    #pragma unroll
    for (int rep = 0; rep < 3; rep++){
      const int r = sr + rep*128;
      const float* bp = &W[(size_t)(wofs + r)*C_ + k0 + sk];
      float4 b0 = *reinterpret_cast<const float4*>(bp);
      float4 b1 = *reinterpret_cast<const float4*>(bp + 4);
      *reinterpret_cast<bfrag*>(&Bs[r][sk]) = cvt8(b0, b1);
    }
    __syncthreads();
    bfrag af[4], bf[6];
    #pragma unroll
    for (int f = 0; f < 4; f++)
      af[f] = *reinterpret_cast<const bfrag*>(&As[wm + f*16 + fr][quad*8]);
    #pragma unroll
    for (int f = 0; f < 6; f++)
      bf[f] = *reinterpret_cast<const bfrag*>(&Bs[wn + f*16 + fr][quad*8]);
    #pragma unroll
    for (int i=0;i<4;i++)
      #pragma unroll
      for (int j=0;j<6;j++)
        acc[i][j] = __builtin_amdgcn_mfma_f32_16x16x32_bf16(af[i], bf[j], acc[i][j], 0, 0, 0);
    __syncthreads();
  }

  // epilogue: D col=lane&15, row=quad*4+reg
  #pragma unroll
  for (int i = 0; i < 4; i++){
    const int rowb = row0 + wm + i*16 + quad*4;
    #pragma unroll
    for (int j = 0; j < 6; j++){
      const int col = wn + j*16 + fr;
      const float bcol = bias[wofs + col];
      const float sc   = scale_inv[col];
      #pragma unroll
      for (int r = 0; r < 4; r++){
        const int row = rowb + r;
        const int n = row & (N_-1);
        float val = acc[i][j][r] + bcol;
        if (mode == 0)      val *= sc;
        else if (mode == 1) val = (val + pe[n*C_ + col]) * sc;
        out[(size_t)row*C_ + col] = f2bfu(val);
      }
    }
  }
}

// ---------------- attention, MFMA (r10 structure), bf16 q/k/v in, fp32 xa out ----------------
#define NC_ 256
__global__ __launch_bounds__(512) void attn_kernel(
    const bfraw* __restrict__ q, const bfraw* __restrict__ k,
    const bfraw* __restrict__ v, const float* __restrict__ power,
    float* __restrict__ xa)
{
  const int bh = blockIdx.x;
  const int b = bh / H_, h = bh % H_;
  __shared__ float pw[64];
  __shared__ __align__(16) unsigned short smem[54912];
  unsigned short* kfT  = smem;                  // [128][264] phase A
  unsigned short* vT   = smem + 33792;          // [80][264]  phase A
  unsigned short* kvBT = smem;                  // [80][136]  phase B (alias)
  unsigned short* qf   = smem + 33792;          // [128][136] phase B (alias)

  const int tid = threadIdx.x;
  const int wave = tid >> 6, lane = tid & 63;
  const int fr = lane & 15, quad = lane >> 4;
  if (tid < 64) pw[tid] = power[h*HD_ + tid];

  const bfraw* kbase = k + (size_t)b*N_*C_ + h*HD_;
  const bfraw* vbase = v + (size_t)b*N_*C_ + h*HD_;

  for (int i = tid; i < 16*NC_; i += 512){
    int e = 64 + (i >> 8);
    int nl = i & (NC_-1);
    vT[e*264 + nl] = (e == 64) ? (unsigned short)0x3F80 : (unsigned short)0;
  }
  __syncthreads();

  f32x4 acc[5] = {};
  for (int chunk = 0; chunk < 2; chunk++){
    const int n0 = chunk * NC_;
    for (int it = 0; it < 32; it++){
      int flat = it*512 + tid;
      int c = flat & 63, nl = flat >> 6;
      float kval = bfu2f(kbase[(size_t)(n0+nl)*C_ + c]);
      float p = pw[c];
      float ax = fabsf(kval);
      float pv = (ax > 0.0f) ? exp2f(p * log2f(ax)) : 0.0f;
      kfT[c*264 + nl]      = f2bfu((kval > 0.0f) ? pv : 0.0f);
      kfT[(64+c)*264 + nl] = f2bfu((kval < 0.0f) ? pv : 0.0f);
      vT[c*264 + nl] = vbase[(size_t)(n0+nl)*C_ + c];
    }
    __syncthreads();
    for (int kk = 0; kk < NC_/32; kk++){
      int ko = kk*32 + quad*8;
      bfrag af = *reinterpret_cast<const bfrag*>(&kfT[(wave*16 + fr)*264 + ko]);
      #pragma unroll
      for (int j = 0; j < 5; j++){
        bfrag bf = *reinterpret_cast<const bfrag*>(&vT[(j*16 + fr)*264 + ko]);
        acc[j] = __builtin_amdgcn_mfma_f32_16x16x32_bf16(af, bf, acc[j], 0, 0, 0);
      }
    }
    __syncthreads();
  }

  const float invN = 1.0f / (float)N_;
  {
    const int dbase = wave*16 + quad*4;
    #pragma unroll
    for (int j = 0; j < 4; j++){
      const int e = j*16 + fr;
      const int dd = (e < 32) ? dbase : (dbase ^ 64);
      ushort4 w4;
      w4.x = f2bfu(acc[j][0] * invN);
      w4.y = f2bfu(acc[j][1] * invN);
      w4.z = f2bfu(acc[j][2] * invN);
      w4.w = f2bfu(acc[j][3] * invN);
      *reinterpret_cast<ushort4*>(&kvBT[e*136 + dd]) = w4;
    }
    if (fr == 0){
      ushort4 wk;
      wk.x = f2bfu(acc[4][0] * invN);
      wk.y = f2bfu(acc[4][1] * invN);
      wk.z = f2bfu(acc[4][2] * invN);
      wk.w = f2bfu(acc[4][3] * invN);
      *reinterpret_cast<ushort4*>(&kvBT[64*136 + dbase]) = wk;
      *reinterpret_cast<ushort4*>(&kvBT[65*136 + (dbase^64)]) = wk;
    }
  }
  __syncthreads();

  const bfraw* qbase = q + (size_t)b*N_*C_ + h*HD_;
  float* xabase = xa + (size_t)b*N_*C_ + h*HD_;
  for (int mc = 0; mc < 4; mc++){
    const int m0 = mc * 128;
    for (int it = 0; it < 16; it++){
      int flat = it*512 + tid;
      int c = flat & 63, nl = flat >> 6;
      float qval = bfu2f(qbase[(size_t)(m0+nl)*C_ + c]);
      float p = pw[c];
      float ax = fabsf(qval);
      float pv = (ax > 0.0f) ? exp2f(p * log2f(ax)) : 0.0f;
      qf[nl*136 + c]      = f2bfu((qval > 0.0f) ? pv : 0.0f);
      qf[nl*136 + 64 + c] = f2bfu((qval < 0.0f) ? pv : 0.0f);
    }
    __syncthreads();
    f32x4 a2[5] = {};
    for (int kk = 0; kk < 4; kk++){
      int ko = kk*32 + quad*8;
      bfrag af = *reinterpret_cast<const bfrag*>(&qf[(wave*16 + fr)*136 + ko]);
      #pragma unroll
      for (int j = 0; j < 5; j++){
        bfrag bf = *reinterpret_cast<const bfrag*>(&kvBT[(j*16 + fr)*136 + ko]);
        a2[j] = __builtin_amdgcn_mfma_f32_16x16x32_bf16(af, bf, a2[j], 0, 0, 0);
      }
    }
    #pragma unroll
    for (int r = 0; r < 4; r++){
      const float zsim = __shfl(a2[4][r], quad*16);
      const float zopp = __shfl(a2[4][r], quad*16 + 1);
      const int n = m0 + wave*16 + quad*4 + r;
      #pragma unroll
      for (int j = 0; j < 4; j++){
        const int e = j*16 + fr;
        const float z = (e < 32) ? zsim : zopp;
        xabase[(size_t)n*C_ + e] = a2[j][r] / (z + 1e-6f);
      }
    }
    __syncthreads();
  }
}

// ---------------- conv (r10 structure), bf16 v in, fp32 xa RMW ----------------
__global__ __launch_bounds__(512) void conv_kernel(
    const bfraw* __restrict__ v, const float* __restrict__ dwc_w,
    const float* __restrict__ dwc_b, float* __restrict__ xa)
{
  const int bh = blockIdx.x;
  const int b = bh / H_, h = bh % H_;
  __shared__ float vol[32][521];
  __shared__ float wv[32][126];
  __shared__ float wb[32];
  const int tid = threadIdx.x;
  const bfraw* vbase = v + (size_t)b*N_*C_ + h*HD_;
  float* xabatch = xa + (size_t)b*N_*C_ + (size_t)h*N_*HD_;

  for (int half = 0; half < 2; half++){
    const int ch0 = half * 32;
    for (int it = 0; it < 32; it++){
      int flat = it*512 + tid;
      int cl = flat & 31, n = flat >> 5;
      vol[cl][n] = bfu2f(vbase[(size_t)n*C_ + ch0 + cl]);
    }
    for (int i = tid; i < 32*125; i += 512){
      int ch = i / 125, wi = i - ch*125;
      wv[ch][wi] = dwc_w[(ch0+ch)*125 + wi];
    }
    if (tid < 32) wb[tid] = dwc_b[ch0 + tid];
    __syncthreads();

    for (int t = 0; t < 4; t++){
      const int task = t*512 + tid;
      const int ch = task & 31;
      const int zy = task >> 5;
      const int z = zy >> 3, yc = zy & 7;
      float o[8];
      const float bias = wb[ch];
      #pragma unroll
      for (int xx = 0; xx < 8; xx++) o[xx] = bias;
      #pragma unroll
      for (int kd = 0; kd < 5; kd++){
        const int zz = z + kd - 2;
        if ((unsigned)zz >= 8u) continue;
        #pragma unroll
        for (int kh = 0; kh < 5; kh++){
          const int yy = yc + kh - 2;
          if ((unsigned)yy >= 8u) continue;
          const float* row = &vol[ch][zz*64 + yy*8];
          float rr[8];
          #pragma unroll
          for (int xx = 0; xx < 8; xx++) rr[xx] = row[xx];
          const float* wrow = &wv[ch][kd*25 + kh*5];
          float w5[5];
          #pragma unroll
          for (int kw = 0; kw < 5; kw++) w5[kw] = wrow[kw];
          #pragma unroll
          for (int xx = 0; xx < 8; xx++){
            #pragma unroll
            for (int kw = 0; kw < 5; kw++){
              const int xi = xx + kw - 2;
              if ((unsigned)xi < 8u) o[xx] = fmaf(w5[kw], rr[xi], o[xx]);
            }
          }
        }
      }
      const int nb = zy * 8;
      #pragma unroll
      for (int xx = 0; xx < 8; xx++){
        const size_t di = (size_t)(nb + xx)*HD_ + ch0 + ch;
        xabatch[di] += o[xx];
      }
    }
    __syncthreads();
  }
}

// ---------------- proj GEMM, MFMA bf16: A = xa(fp32)*g(bf16), fp32 out ----------------
__global__ __launch_bounds__(256) void proj_kernel(
    const float* __restrict__ xa, const bfraw* __restrict__ g,
    const float* __restrict__ Wp, const float* __restrict__ bp,
    float* __restrict__ out)
{
  __shared__ short As[128][40];
  __shared__ short Bs[128][40];

  const int tid  = threadIdx.x;
  const int row0 = blockIdx.y * 128;
  const int col0 = blockIdx.x * 128;
  const int wave = tid >> 6, lane = tid & 63;
  const int wm = (wave >> 1) * 64, wn = (wave & 1) * 64;
  const int fr = lane & 15, quad = lane >> 4;
  const int sr = tid >> 2;
  const int sk = (tid & 3) * 8;

  f32x4 acc[4][4] = {};

  for (int k0 = 0; k0 < C_; k0 += 32){
    #pragma unroll
    for (int half = 0; half < 2; half++){
      const int r = sr + half*64;
      const size_t aidx = (size_t)(row0 + r)*C_ + k0 + sk;
      float4 x0 = *reinterpret_cast<const float4*>(&xa[aidx]);
      float4 x1 = *reinterpret_cast<const float4*>(&xa[aidx + 4]);
      const ushort4 gu0 = *reinterpret_cast<const ushort4*>(&g[aidx]);
      const ushort4 gu1 = *reinterpret_cast<const ushort4*>(&g[aidx + 4]);
      x0.x*=bfu2f(gu0.x); x0.y*=bfu2f(gu0.y); x0.z*=bfu2f(gu0.z); x0.w*=bfu2f(gu0.w);
      x1.x*=bfu2f(gu1.x); x1.y*=bfu2f(gu1.y); x1.z*=bfu2f(gu1.z); x1.w*=bfu2f(gu1.w);
      const float* bp2 = &Wp[(size_t)(col0 + r)*C_ + k0 + sk];
      float4 b0 = *reinterpret_cast<const float4*>(bp2);
      float4 b1 = *reinterpret_cast<const float4*>(bp2 + 4);
      *reinterpret_cast<bfrag*>(&As[r][sk]) = cvt8(x0, x1);
      *reinterpret_cast<bfrag*>(&Bs[r][sk]) = cvt8(b0, b1);
    }
    __syncthreads();
    bfrag af[4], bf[4];
    #pragma unroll
    for (int f = 0; f < 4; f++){
      af[f] = *reinterpret_cast<const bfrag*>(&As[wm + f*16 + fr][quad*8]);
      bf[f] = *reinterpret_cast<const bfrag*>(&Bs[wn + f*16 + fr][quad*8]);
    }
    #pragma unroll
    for (int i=0;i<4;i++)
      #pragma unroll
      for (int j=0;j<4;j++)
        acc[i][j] = __builtin_amdgcn_mfma_f32_16x16x32_bf16(af[i], bf[j], acc[i][j], 0, 0, 0);
    __syncthreads();
  }

  #pragma unroll
  for (int i = 0; i < 4; i++){
    const int rowb = row0 + wm + i*16 + quad*4;
    #pragma unroll
    for (int j = 0; j < 4; j++){
      const int col = col0 + wn + j*16 + fr;
      const float bcol = bp[col];
      #pragma unroll
      for (int r = 0; r < 4; r++){
        out[(size_t)(rowb + r)*C_ + col] = acc[i][j][r] + bcol;
      }
    }
  }
}

extern "C" void kernel_launch(void* const* d_in, const int* in_sizes, int n_in,
                              void* d_out, int out_size, void* d_ws, size_t ws_size,
                              hipStream_t stream){
  float* out = (float*)d_out;

  const int expect[11] = {6291456, 6291456, 589824, 1536, 147456, 384, 8000, 64, 384, 384, 196608};
  bool ok = (n_in == 11);
  for (int i = 0; ok && i < 11; i++) ok = (in_sizes[i] == expect[i]);
  if (!ok){
    sentinel_kernel<<<(out_size+255)/256, 256, 0, stream>>>(out, out_size);
    return;
  }

  const float* x    = (const float*)d_in[0];
  const float* y    = (const float*)d_in[1];
  const float* W    = (const float*)d_in[2];
  const float* bq   = (const float*)d_in[3];
  const float* Wp   = (const float*)d_in[4];
  const float* bp   = (const float*)d_in[5];
  const float* dwcw = (const float*)d_in[6];
  const float* dwcb = (const float*)d_in[7];
  const float* pwp  = (const float*)d_in[8];
  const float* scp  = (const float*)d_in[9];
  const float* pe   = (const float*)d_in[10];

  const size_t SZ = (size_t)M_ * C_;
  bfraw* q = (bfraw*)d_ws;
  bfraw* k = q + SZ;
  bfraw* v = k + SZ;
  bfraw* g = v + SZ;
  float* xa = (float*)(g + SZ);
  float* scale_inv = xa + SZ;
  float* power     = scale_inv + 512;

  param_kernel<<<1, 512, 0, stream>>>(scp, pwp, scale_inv, power);
  gemm_qkvg<<<dim3(M_/128, 4), 512, 0, stream>>>(x, y, W, bq, pe, scale_inv, q, k, v, g);
  attn_kernel<<<dim3(B_*H_), 512, 0, stream>>>(q, k, v, power, xa);
  conv_kernel<<<dim3(B_*H_), 512, 0, stream>>>(v, dwcw, dwcb, xa);
  proj_kernel<<<dim3(C_/128, M_/128), 256, 0, stream>>>(xa, g, Wp, bp, out);
}